// Round 3
// baseline (3059.424 us; speedup 1.0000x reference)
//
#include <hip/hip_runtime.h>

// SparseGCNConv: out = segment_sum(norm * f[src], dst, N) @ W^T + bias
// R3: g = f@W^T in packed bf16; edges binned into 782 buckets of 128 dst-nodes
// (LDS-ranked dense runs, ~50K global cursor atomics); pull = one block per
// bucket with 64KB LDS fp32 accumulators + LDS float atomics; coalesced slab
// write + bias. Deletes R2's per-node sort (fill_kernel: 198MB HBM write amp,
// 264us) and per-node hist/scan.

#define NN   100000
#define NE   3200000
#define D    128
#define NBKT 782  // ceil(NN/128); bucket b = dst >> 7

static __device__ __forceinline__ unsigned short f2bf(float x) {
  unsigned u = __float_as_uint(x);
  u += 0x7FFFu + ((u >> 16) & 1u);  // RTNE
  return (unsigned short)(u >> 16);
}

// ---------------------------------------------------------------------------
// g = f @ W^T, output packed bf16: row n stores [ch0,ch64,ch1,ch65,...] so a
// single 4B load at ushort-offset 2*lane yields channels {lane, lane+64}.
__global__ __launch_bounds__(256) void gemm_kernel(
    const float* __restrict__ f, const float* __restrict__ w,
    unsigned short* __restrict__ gb) {
  __shared__ float wlds[D * D];  // 64 KB, XOR-swizzled (store & read conflict-free)
  const int t = threadIdx.x;
  for (int i = t; i < D * D; i += 256) {
    int c = i >> 7, k = i & 127;
    wlds[(c << 7) + (k ^ (c & 31))] = w[i];
  }
  __syncthreads();

  const int c = t & 127;
  const int cx = c & 31;
  const int cbase = c << 7;
  const int jbase = __builtin_amdgcn_readfirstlane((t >> 7) << 3);  // 0 or 8
  const long nb = (long)blockIdx.x * 16 + jbase;
  const float* __restrict__ frow = f + nb * D;

  float acc[8] = {0.f, 0.f, 0.f, 0.f, 0.f, 0.f, 0.f, 0.f};
#pragma unroll 4
  for (int k = 0; k < D; ++k) {
    float wv = wlds[cbase + (k ^ cx)];
#pragma unroll
    for (int j = 0; j < 8; ++j) acc[j] += frow[j * D + k] * wv;
  }
  // packed position: ch<64 -> 2*ch ; ch>=64 -> 2*(ch-64)+1
  const int pos = (c < 64) ? (c << 1) : (((c - 64) << 1) + 1);
#pragma unroll
  for (int j = 0; j < 8; ++j) gb[(nb + j) * D + pos] = f2bf(acc[j]);
}

// ---------------------------------------------------------------------------
// Bucket histogram (782 counters), LDS-aggregated: ~300K global atomics total.
__global__ __launch_bounds__(256) void hist_kernel(const int* __restrict__ dst,
                                                   int* __restrict__ gcnt) {
  __shared__ int h[NBKT];
  const int t = threadIdx.x;
  for (int b = t; b < NBKT; b += 256) h[b] = 0;
  __syncthreads();
  const int base = blockIdx.x * 4096;
#pragma unroll
  for (int i = 0; i < 16; ++i) {
    int e = base + i * 256 + t;
    if (e < NE) atomicAdd(&h[dst[e] >> 7], 1);
  }
  __syncthreads();
  for (int b = t; b < NBKT; b += 256)
    if (h[b]) atomicAdd(&gcnt[b], h[b]);
}

// Exclusive scan of 782 bucket counts (single block); seeds cursors.
__global__ __launch_bounds__(1024) void scan_kernel(const int* __restrict__ gcnt,
                                                    int* __restrict__ bstart,
                                                    int* __restrict__ cur) {
  __shared__ int s[1024];
  const int t = threadIdx.x;
  int v = (t < NBKT) ? gcnt[t] : 0;
  s[t] = v;
  __syncthreads();
#pragma unroll
  for (int off = 1; off < 1024; off <<= 1) {
    int x = (t >= off) ? s[t - off] : 0;
    __syncthreads();
    s[t] += x;
    __syncthreads();
  }
  if (t < NBKT) {
    int st = s[t] - v;
    bstart[t] = st;
    cur[t] = st;
  }
  if (t == 0) bstart[NBKT] = NE;
}

// ---------------------------------------------------------------------------
// Bin edges into buckets. Per-block LDS histogram -> one global cursor atomic
// per (block,bucket) -> LDS-ranked scatter: each block writes dense per-bucket
// runs (avg 8192/782 ~ 10.5 entries = 84B), 782 concurrent frontiers.
// bufA entry: {src | dstLocal<<24, norm_bits}
__global__ __launch_bounds__(256) void bin_kernel(
    const int* __restrict__ src, const int* __restrict__ dst,
    const float* __restrict__ norm, int* __restrict__ cur,
    int2* __restrict__ bufA) {
  __shared__ int bcnt[NBKT];
  __shared__ int bbase[NBKT];
  const int t = threadIdx.x;
  for (int b = t; b < NBKT; b += 256) bcnt[b] = 0;
  __syncthreads();
  const int base = blockIdx.x * 8192;
#pragma unroll
  for (int i = 0; i < 32; ++i) {
    int e = base + i * 256 + t;
    if (e < NE) atomicAdd(&bcnt[dst[e] >> 7], 1);
  }
  __syncthreads();
  for (int b = t; b < NBKT; b += 256) {
    int c = bcnt[b];
    if (c) bbase[b] = atomicAdd(&cur[b], c);
    bcnt[b] = 0;  // reuse as rank counter
  }
  __syncthreads();
#pragma unroll
  for (int i = 0; i < 32; ++i) {
    int e = base + i * 256 + t;
    if (e < NE) {
      int d = dst[e];
      int b = d >> 7;
      int r = atomicAdd(&bcnt[b], 1);
      int2 m;
      m.x = src[e] | ((d & 127) << 24);  // src < 2^17 fits low 24 bits
      m.y = __float_as_int(norm[e]);
      bufA[bbase[b] + r] = m;
    }
  }
}

// ---------------------------------------------------------------------------
// Pull: one block (512 thr = 8 waves) per 128-node bucket. 64KB LDS fp32
// accumulators; lane owns channels {lane, lane+64} -> LDS bank = lane&31,
// 2-way aliasing = free. 4 edges in flight per wave (loads unconditional via
// clamped index; only the LDS adds are guarded) to hide L3 gather latency.
__global__ __launch_bounds__(512) void pull_kernel(
    const unsigned short* __restrict__ gb, const int* __restrict__ bstart,
    const int2* __restrict__ bufA, const float* __restrict__ bias,
    float* __restrict__ out) {
  __shared__ float acc[128 * D];  // 64 KB
  const int t = threadIdx.x;
  const int lane = t & 63;
  const int w = t >> 6;  // wave 0..7
  const int b = blockIdx.x;

  for (int i = t; i < 128 * D; i += 512) acc[i] = 0.f;
  __syncthreads();

  const int beg = bstart[b];
  const int end = bstart[b + 1];

  for (int e = beg + w; e < end; e += 32) {
    const int e1 = min(e + 8, end - 1);
    const int e2 = min(e + 16, end - 1);
    const int e3 = min(e + 24, end - 1);
    const int2 m0 = bufA[e];
    const int2 m1 = bufA[e1];
    const int2 m2 = bufA[e2];
    const int2 m3 = bufA[e3];
    const unsigned q0 = *(const unsigned*)(gb + ((long)(m0.x & 0xFFFFFF) << 7) + (lane << 1));
    const unsigned q1 = *(const unsigned*)(gb + ((long)(m1.x & 0xFFFFFF) << 7) + (lane << 1));
    const unsigned q2 = *(const unsigned*)(gb + ((long)(m2.x & 0xFFFFFF) << 7) + (lane << 1));
    const unsigned q3 = *(const unsigned*)(gb + ((long)(m3.x & 0xFFFFFF) << 7) + (lane << 1));
    {
      const int nl = (m0.x >> 24) & 127;
      const float nr = __int_as_float(m0.y);
      atomicAdd(&acc[(nl << 7) + lane], nr * __uint_as_float(q0 << 16));
      atomicAdd(&acc[(nl << 7) + 64 + lane], nr * __uint_as_float(q0 & 0xFFFF0000u));
    }
    if (e + 8 < end) {
      const int nl = (m1.x >> 24) & 127;
      const float nr = __int_as_float(m1.y);
      atomicAdd(&acc[(nl << 7) + lane], nr * __uint_as_float(q1 << 16));
      atomicAdd(&acc[(nl << 7) + 64 + lane], nr * __uint_as_float(q1 & 0xFFFF0000u));
    }
    if (e + 16 < end) {
      const int nl = (m2.x >> 24) & 127;
      const float nr = __int_as_float(m2.y);
      atomicAdd(&acc[(nl << 7) + lane], nr * __uint_as_float(q2 << 16));
      atomicAdd(&acc[(nl << 7) + 64 + lane], nr * __uint_as_float(q2 & 0xFFFF0000u));
    }
    if (e + 24 < end) {
      const int nl = (m3.x >> 24) & 127;
      const float nr = __int_as_float(m3.y);
      atomicAdd(&acc[(nl << 7) + lane], nr * __uint_as_float(q3 << 16));
      atomicAdd(&acc[(nl << 7) + 64 + lane], nr * __uint_as_float(q3 & 0xFFFF0000u));
    }
  }
  __syncthreads();

  const int nbase = b << 7;
  const float b0 = bias[lane];
  const float b1 = bias[64 + lane];
  for (int nl = w; nl < 128; nl += 8) {
    const int n = nbase + nl;
    if (n < NN) {
      out[(long)n * D + lane] = acc[(nl << 7) + lane] + b0;
      out[(long)n * D + 64 + lane] = acc[(nl << 7) + 64 + lane] + b1;
    }
  }
}

// ---------------------------------------------------------------------------
// Fallback path (only if ws too small): R1 fp32 gemm + bias init + atomics.
__global__ __launch_bounds__(256) void gemm_f32_kernel(
    const float* __restrict__ f, const float* __restrict__ w,
    float* __restrict__ g) {
  __shared__ float wlds[D * D];
  const int t = threadIdx.x;
  for (int i = t; i < D * D; i += 256) {
    int c = i >> 7, k = i & 127;
    wlds[(c << 7) + (k ^ (c & 31))] = w[i];
  }
  __syncthreads();
  const int c = t & 127;
  const int cx = c & 31;
  const int cbase = c << 7;
  const int jbase = __builtin_amdgcn_readfirstlane((t >> 7) << 3);
  const long nb = (long)blockIdx.x * 16 + jbase;
  const float* __restrict__ frow = f + nb * D;
  float acc[8] = {0.f, 0.f, 0.f, 0.f, 0.f, 0.f, 0.f, 0.f};
#pragma unroll 4
  for (int k = 0; k < D; ++k) {
    float wv = wlds[cbase + (k ^ cx)];
#pragma unroll
    for (int j = 0; j < 8; ++j) acc[j] += frow[j * D + k] * wv;
  }
#pragma unroll
  for (int j = 0; j < 8; ++j) g[(nb + j) * D + c] = acc[j];
}

__global__ __launch_bounds__(256) void init_kernel(
    const float* __restrict__ bias, float4* __restrict__ out) {
  const int i = blockIdx.x * 256 + threadIdx.x;
  const float4* b4 = (const float4*)bias;
  out[i] = b4[i & 31];
}

__global__ __launch_bounds__(256) void scatter_kernel(
    const float* __restrict__ g, const float* __restrict__ norm,
    const int* __restrict__ src, const int* __restrict__ dst,
    float* __restrict__ out) {
  const long tid = (long)blockIdx.x * 256 + threadIdx.x;
  const int e = (int)(tid >> 5);
  if (e >= NE) return;
  const int ch = (int)(tid & 31) << 2;
  const int s = src[e];
  const int d = dst[e];
  const float nr = norm[e];
  const float4 gv = *(const float4*)(g + (long)s * D + ch);
  float* op = out + (long)d * D + ch;
  unsafeAtomicAdd(op + 0, nr * gv.x);
  unsafeAtomicAdd(op + 1, nr * gv.y);
  unsafeAtomicAdd(op + 2, nr * gv.z);
  unsafeAtomicAdd(op + 3, nr * gv.w);
}

// ---------------------------------------------------------------------------
extern "C" void kernel_launch(void* const* d_in, const int* in_sizes, int n_in,
                              void* d_out, int out_size, void* d_ws,
                              size_t ws_size, hipStream_t stream) {
  const float* features = (const float*)d_in[0];
  const float* norm     = (const float*)d_in[1];
  const int*   src      = (const int*)d_in[2];
  const int*   dst      = (const int*)d_in[3];
  const float* weight   = (const float*)d_in[4];
  const float* bias     = (const float*)d_in[5];
  float* out = (float*)d_out;

  // ws layout
  char* ws = (char*)d_ws;
  unsigned short* gb = (unsigned short*)ws;            // 25,600,000 B (bf16 g)
  int2* bufA   = (int2*)(ws + 25600000);               // 25,600,000 B
  int*  gcnt   = (int*)(ws + 51200000);                // 3,128 B
  int*  bstart = (int*)(ws + 51203200);                // 3,132 B
  int*  cur    = (int*)(ws + 51206400);                // 3,128 B
  const size_t need = 51210000;

  if (ws_size >= need) {
    hipMemsetAsync(gcnt, 0, NBKT * sizeof(int), stream);
    hipLaunchKernelGGL(gemm_kernel, dim3(NN / 16), dim3(256), 0, stream,
                       features, weight, gb);
    hipLaunchKernelGGL(hist_kernel, dim3((NE + 4095) / 4096), dim3(256), 0,
                       stream, dst, gcnt);
    hipLaunchKernelGGL(scan_kernel, dim3(1), dim3(1024), 0, stream,
                       gcnt, bstart, cur);
    hipLaunchKernelGGL(bin_kernel, dim3((NE + 8191) / 8192), dim3(256), 0,
                       stream, src, dst, norm, cur, bufA);
    hipLaunchKernelGGL(pull_kernel, dim3(NBKT), dim3(512), 0, stream,
                       gb, bstart, bufA, bias, out);
  } else {
    float* g = (float*)ws;
    hipLaunchKernelGGL(gemm_f32_kernel, dim3(NN / 16), dim3(256), 0, stream,
                       features, weight, g);
    hipLaunchKernelGGL(init_kernel, dim3((NN * D / 4) / 256), dim3(256), 0,
                       stream, bias, (float4*)out);
    hipLaunchKernelGGL(scatter_kernel, dim3((long)NE * 32 / 256), dim3(256), 0,
                       stream, g, norm, src, dst, out);
  }
}

// Round 5
// 604.211 us; speedup vs baseline: 5.0635x; 5.0635x over previous
//
#include <hip/hip_runtime.h>

// SparseGCNConv: out = segment_sum(norm * f[src], dst, N) @ W^T + bias
// R5: fully atomic-free accumulate path.
//   1) gemm: g = f@W^T, packed bf16 (proven R3)
//   2) hist/scan/bin: edges -> 1563 buckets of 64 dst nodes (dense runs)
//   3) sort: per-bucket counting sort by node in LDS (int atomics only),
//      emits node-sorted bufB + global row_ptr
//   4) pull: one wave per node, 8 edges in flight, register float2 accs,
//      plain loads/stores, ZERO atomics, ZERO LDS.
// R3/R4 post-mortem: both the 2655us stall (R3) and the absmax=2.87
// corruption (R4) were in the LDS fp-atomic path -- removed entirely.

#define NN    100000
#define NE    3200000
#define D     128
#define NBKT2 1563  // ceil(NN/64); bucket b = dst >> 6

static __device__ __forceinline__ unsigned short f2bf(float x) {
  unsigned u = __float_as_uint(x);
  u += 0x7FFFu + ((u >> 16) & 1u);  // RTNE
  return (unsigned short)(u >> 16);
}

// ---------------------------------------------------------------------------
// g = f @ W^T, packed bf16: row n = [ch0,ch64,ch1,ch65,...]; one 4B load at
// ushort-offset 2*lane yields channels {lane, lane+64}.  (proven R3)
__global__ __launch_bounds__(256) void gemm_kernel(
    const float* __restrict__ f, const float* __restrict__ w,
    unsigned short* __restrict__ gb) {
  __shared__ float wlds[D * D];  // 64 KB, XOR-swizzled
  const int t = threadIdx.x;
  for (int i = t; i < D * D; i += 256) {
    int c = i >> 7, k = i & 127;
    wlds[(c << 7) + (k ^ (c & 31))] = w[i];
  }
  __syncthreads();

  const int c = t & 127;
  const int cx = c & 31;
  const int cbase = c << 7;
  const int jbase = __builtin_amdgcn_readfirstlane((t >> 7) << 3);  // 0 or 8
  const long nb = (long)blockIdx.x * 16 + jbase;
  const float* __restrict__ frow = f + nb * D;

  float acc[8] = {0.f, 0.f, 0.f, 0.f, 0.f, 0.f, 0.f, 0.f};
#pragma unroll 4
  for (int k = 0; k < D; ++k) {
    float wv = wlds[cbase + (k ^ cx)];
#pragma unroll
    for (int j = 0; j < 8; ++j) acc[j] += frow[j * D + k] * wv;
  }
  const int pos = (c < 64) ? (c << 1) : (((c - 64) << 1) + 1);
#pragma unroll
  for (int j = 0; j < 8; ++j) gb[(nb + j) * D + pos] = f2bf(acc[j]);
}

// ---------------------------------------------------------------------------
// Bucket histogram (1563 counters), LDS-aggregated int atomics.
__global__ __launch_bounds__(256) void hist_kernel(const int* __restrict__ dst,
                                                   int* __restrict__ gcnt) {
  __shared__ int h[NBKT2];
  const int t = threadIdx.x;
  for (int b = t; b < NBKT2; b += 256) h[b] = 0;
  __syncthreads();
  const int base = blockIdx.x * 4096;
#pragma unroll
  for (int i = 0; i < 16; ++i) {
    int e = base + i * 256 + t;
    if (e < NE) atomicAdd(&h[dst[e] >> 6], 1);
  }
  __syncthreads();
  for (int b = t; b < NBKT2; b += 256)
    if (h[b]) atomicAdd(&gcnt[b], h[b]);
}

// Exclusive scan of 1563 counts. Simple & verifiable: stage 2048 in LDS,
// wave 0 does chunk-sums + shfl-scan + chunk-rewrite. One-off tiny kernel.
__global__ __launch_bounds__(1024) void scan_kernel(const int* __restrict__ gcnt,
                                                    int* __restrict__ bstart,
                                                    int* __restrict__ cur,
                                                    int* __restrict__ row_ptr) {
  __shared__ int s[2048];
  const int t = threadIdx.x;
  s[t] = (t < NBKT2) ? gcnt[t] : 0;
  s[t + 1024] = (t + 1024 < NBKT2) ? gcnt[t + 1024] : 0;
  __syncthreads();
  if (t < 64) {
    int part = 0;
#pragma unroll
    for (int i = 0; i < 32; ++i) part += s[(t << 5) + i];
    int inc = part;
#pragma unroll
    for (int off = 1; off < 64; off <<= 1) {
      int x = __shfl_up(inc, off, 64);
      if (t >= off) inc += x;
    }
    int run = inc - part;  // exclusive prefix of this 32-chunk
#pragma unroll
    for (int i = 0; i < 32; ++i) {
      int idx = (t << 5) + i;
      int v = s[idx];
      s[idx] = run;
      run += v;
    }
  }
  __syncthreads();
  if (t < NBKT2) { bstart[t] = s[t]; cur[t] = s[t]; }
  if (t + 1024 < NBKT2) { bstart[t + 1024] = s[t + 1024]; cur[t + 1024] = s[t + 1024]; }
  if (t == 0) { bstart[NBKT2] = NE; row_ptr[NN] = NE; }
}

// ---------------------------------------------------------------------------
// Bin edges into buckets: per-block LDS hist -> one cursor atomic per
// (block,bucket) -> LDS-ranked dense-run scatter. Entry {src|nl<<24, norm}.
__global__ __launch_bounds__(512) void bin_kernel(
    const int* __restrict__ src, const int* __restrict__ dst,
    const float* __restrict__ norm, int* __restrict__ cur,
    int2* __restrict__ bufA) {
  __shared__ int bcnt[NBKT2];
  __shared__ int bbase[NBKT2];
  const int t = threadIdx.x;
  for (int b = t; b < NBKT2; b += 512) bcnt[b] = 0;
  __syncthreads();
  const int base = blockIdx.x * 16384;
#pragma unroll
  for (int i = 0; i < 32; ++i) {
    int e = base + i * 512 + t;
    if (e < NE) atomicAdd(&bcnt[dst[e] >> 6], 1);
  }
  __syncthreads();
  for (int b = t; b < NBKT2; b += 512) {
    int c = bcnt[b];
    if (c) bbase[b] = atomicAdd(&cur[b], c);
    bcnt[b] = 0;  // reuse as rank
  }
  __syncthreads();
#pragma unroll
  for (int i = 0; i < 32; ++i) {
    int e = base + i * 512 + t;
    if (e < NE) {
      int d = dst[e];
      int b = d >> 6;
      int r = atomicAdd(&bcnt[b], 1);
      int2 m;
      m.x = src[e] | ((d & 63) << 24);  // src < 2^17
      m.y = __float_as_int(norm[e]);
      bufA[bbase[b] + r] = m;
    }
  }
}

// ---------------------------------------------------------------------------
// Per-bucket counting sort by local node (64 bins). Int LDS atomics only.
// Writes node-sorted bufB (dense, within bucket's contiguous region) and
// global row_ptr[n] = start of node n's run.
__global__ __launch_bounds__(256) void sort_kernel(
    const int2* __restrict__ bufA, const int* __restrict__ bstart,
    int2* __restrict__ bufB, int* __restrict__ row_ptr) {
  __shared__ int lcnt[64];
  __shared__ int lbase[64];
  const int b = blockIdx.x;
  const int t = threadIdx.x;
  const int beg = bstart[b];
  const int end = bstart[b + 1];
  if (t < 64) lcnt[t] = 0;
  __syncthreads();
  for (int e = beg + t; e < end; e += 256) {
    int2 m = bufA[e];
    atomicAdd(&lcnt[(m.x >> 24) & 63], 1);
  }
  __syncthreads();
  if (t < 64) {  // wave 0: exclusive shfl-scan of 64 counts
    int v = lcnt[t];
    int inc = v;
#pragma unroll
    for (int off = 1; off < 64; off <<= 1) {
      int x = __shfl_up(inc, off, 64);
      if (t >= off) inc += x;
    }
    int ex = inc - v;
    lbase[t] = ex;
    int n = (b << 6) + t;
    if (n < NN) row_ptr[n] = beg + ex;
    lcnt[t] = 0;  // reuse as rank
  }
  __syncthreads();
  for (int e = beg + t; e < end; e += 256) {
    int2 m = bufA[e];
    int nl = (m.x >> 24) & 63;
    int r = atomicAdd(&lcnt[nl], 1);
    int2 o;
    o.x = m.x & 0xFFFFFF;  // pure src
    o.y = m.y;
    bufB[beg + lbase[nl] + r] = o;
  }
}

// ---------------------------------------------------------------------------
// Pull: one wave per node. Lane owns channels {lane, lane+64}. 8 edges in
// flight -> 8 independent float2 register accumulators. No atomics, no LDS.
__global__ __launch_bounds__(256) void pull_kernel(
    const unsigned short* __restrict__ gb, const int* __restrict__ row_ptr,
    const int2* __restrict__ bufB, const float* __restrict__ bias,
    float* __restrict__ out) {
  const int n = blockIdx.x * 4 + (threadIdx.x >> 6);
  if (n >= NN) return;
  const int lane = threadIdx.x & 63;
  const int beg = row_ptr[n];
  const int end = row_ptr[n + 1];

  float a0[8] = {0.f, 0.f, 0.f, 0.f, 0.f, 0.f, 0.f, 0.f};
  float a1[8] = {0.f, 0.f, 0.f, 0.f, 0.f, 0.f, 0.f, 0.f};

  for (int e0 = beg; e0 < end; e0 += 8) {
    int2 m[8];
    unsigned q[8];
#pragma unroll
    for (int j = 0; j < 8; ++j) m[j] = bufB[min(e0 + j, end - 1)];
#pragma unroll
    for (int j = 0; j < 8; ++j)
      q[j] = *(const unsigned*)(gb + ((long)m[j].x << 7) + (lane << 1));
#pragma unroll
    for (int j = 0; j < 8; ++j) {
      if (e0 + j < end) {  // wave-uniform guard
        const float nr = __int_as_float(m[j].y);
        a0[j] += nr * __uint_as_float(q[j] << 16);
        a1[j] += nr * __uint_as_float(q[j] & 0xFFFF0000u);
      }
    }
  }
  const float s0 = ((a0[0] + a0[1]) + (a0[2] + a0[3])) +
                   ((a0[4] + a0[5]) + (a0[6] + a0[7]));
  const float s1 = ((a1[0] + a1[1]) + (a1[2] + a1[3])) +
                   ((a1[4] + a1[5]) + (a1[6] + a1[7]));
  out[(long)n * D + lane] = s0 + bias[lane];
  out[(long)n * D + 64 + lane] = s1 + bias[64 + lane];
}

// ---------------------------------------------------------------------------
// Fallback (ws too small): R1 path.
__global__ __launch_bounds__(256) void gemm_f32_kernel(
    const float* __restrict__ f, const float* __restrict__ w,
    float* __restrict__ g) {
  __shared__ float wlds[D * D];
  const int t = threadIdx.x;
  for (int i = t; i < D * D; i += 256) {
    int c = i >> 7, k = i & 127;
    wlds[(c << 7) + (k ^ (c & 31))] = w[i];
  }
  __syncthreads();
  const int c = t & 127;
  const int cx = c & 31;
  const int cbase = c << 7;
  const int jbase = __builtin_amdgcn_readfirstlane((t >> 7) << 3);
  const long nb = (long)blockIdx.x * 16 + jbase;
  const float* __restrict__ frow = f + nb * D;
  float acc[8] = {0.f, 0.f, 0.f, 0.f, 0.f, 0.f, 0.f, 0.f};
#pragma unroll 4
  for (int k = 0; k < D; ++k) {
    float wv = wlds[cbase + (k ^ cx)];
#pragma unroll
    for (int j = 0; j < 8; ++j) acc[j] += frow[j * D + k] * wv;
  }
#pragma unroll
  for (int j = 0; j < 8; ++j) g[(nb + j) * D + c] = acc[j];
}

__global__ __launch_bounds__(256) void init_kernel(
    const float* __restrict__ bias, float4* __restrict__ out) {
  const int i = blockIdx.x * 256 + threadIdx.x;
  const float4* b4 = (const float4*)bias;
  out[i] = b4[i & 31];
}

__global__ __launch_bounds__(256) void scatter_kernel(
    const float* __restrict__ g, const float* __restrict__ norm,
    const int* __restrict__ src, const int* __restrict__ dst,
    float* __restrict__ out) {
  const long tid = (long)blockIdx.x * 256 + threadIdx.x;
  const int e = (int)(tid >> 5);
  if (e >= NE) return;
  const int ch = (int)(tid & 31) << 2;
  const int s = src[e];
  const int d = dst[e];
  const float nr = norm[e];
  const float4 gv = *(const float4*)(g + (long)s * D + ch);
  float* op = out + (long)d * D + ch;
  unsafeAtomicAdd(op + 0, nr * gv.x);
  unsafeAtomicAdd(op + 1, nr * gv.y);
  unsafeAtomicAdd(op + 2, nr * gv.z);
  unsafeAtomicAdd(op + 3, nr * gv.w);
}

// ---------------------------------------------------------------------------
extern "C" void kernel_launch(void* const* d_in, const int* in_sizes, int n_in,
                              void* d_out, int out_size, void* d_ws,
                              size_t ws_size, hipStream_t stream) {
  const float* features = (const float*)d_in[0];
  const float* norm     = (const float*)d_in[1];
  const int*   src      = (const int*)d_in[2];
  const int*   dst      = (const int*)d_in[3];
  const float* weight   = (const float*)d_in[4];
  const float* bias     = (const float*)d_in[5];
  float* out = (float*)d_out;

  char* ws = (char*)d_ws;
  unsigned short* gb = (unsigned short*)ws;      // [0, 25,600,000)
  int2* bufA    = (int2*)(ws + 25600000);        // [25.6M, 51.2M)
  int2* bufB    = (int2*)(ws + 51200000);        // [51.2M, 76.8M)
  int*  row_ptr = (int*)(ws + 76800000);         // 100001 ints -> 400,004 B
  int*  gcnt    = (int*)(ws + 77200008);         // 6,252 B
  int*  bstart  = (int*)(ws + 77206264);         // 6,256 B
  int*  cur     = (int*)(ws + 77212524);         // 6,252 B
  const size_t need = 77218776;                  // ws >= 77,602,176 proven (R2)

  if (ws_size >= need) {
    hipMemsetAsync(gcnt, 0, NBKT2 * sizeof(int), stream);
    hipLaunchKernelGGL(gemm_kernel, dim3(NN / 16), dim3(256), 0, stream,
                       features, weight, gb);
    hipLaunchKernelGGL(hist_kernel, dim3((NE + 4095) / 4096), dim3(256), 0,
                       stream, dst, gcnt);
    hipLaunchKernelGGL(scan_kernel, dim3(1), dim3(1024), 0, stream,
                       gcnt, bstart, cur, row_ptr);
    hipLaunchKernelGGL(bin_kernel, dim3((NE + 16383) / 16384), dim3(512), 0,
                       stream, src, dst, norm, cur, bufA);
    hipLaunchKernelGGL(sort_kernel, dim3(NBKT2), dim3(256), 0, stream,
                       bufA, bstart, bufB, row_ptr);
    hipLaunchKernelGGL(pull_kernel, dim3((NN + 3) / 4), dim3(256), 0, stream,
                       gb, row_ptr, bufB, bias, out);
  } else {
    float* g = (float*)ws;
    hipLaunchKernelGGL(gemm_f32_kernel, dim3(NN / 16), dim3(256), 0, stream,
                       features, weight, g);
    hipLaunchKernelGGL(init_kernel, dim3((NN * D / 4) / 256), dim3(256), 0,
                       stream, bias, (float4*)out);
    hipLaunchKernelGGL(scatter_kernel, dim3((long)NE * 32 / 256), dim3(256), 0,
                       stream, g, norm, src, dst, out);
  }
}

// Round 6
// 437.283 us; speedup vs baseline: 6.9964x; 1.3817x over previous
//
#include <hip/hip_runtime.h>

// SparseGCNConv: out = segment_sum(norm * f[src], dst, N) @ W^T + bias
// R6: R5's proven atomic-free pipeline, with the fp32 VALU gemm (204us,
// 21% occupancy, LDS-capped) replaced by a per-wave MFMA bf16 gemm
// (m97-verified operand layouts; W pre-converted to fragment-ordered bf16
// by cvtw). gb is now plain row-major bf16; pull lane owns channels
// {2*lane, 2*lane+1}.

#define NN    100000
#define NE    3200000
#define D     128
#define NBKT2 1563  // ceil(NN/64); bucket b = dst >> 6
#define NTILE 6250  // NN/16 node tiles (exact)

typedef __attribute__((ext_vector_type(8))) short bf16x8;
typedef __attribute__((ext_vector_type(4))) float f32x4;

static __device__ __forceinline__ unsigned short f2bf(float x) {
  unsigned u = __float_as_uint(x);
  u += 0x7FFFu + ((u >> 16) & 1u);  // RTNE
  return (unsigned short)(u >> 16);
}

// ---------------------------------------------------------------------------
// W [128][128] fp32 -> bf16 in MFMA B-fragment order:
// wfrag[((tc*4+ks)*64 + lane)*8 + j] = bf16(w[c][k])
//   where c = tc*16 + (lane&15), k = ks*32 + (lane>>4)*8 + j.
__global__ __launch_bounds__(256) void cvtw_kernel(
    const float* __restrict__ w, unsigned short* __restrict__ wfrag) {
  const int i = blockIdx.x * 256 + threadIdx.x;  // 16384 elems, 64 blocks
  const int c = i >> 7, k = i & 127;
  const int pos = ((((c >> 4) << 2) + (k >> 5)) * 64 +
                   (((k >> 3) & 3) << 4) + (c & 15)) * 8 + (k & 7);
  wfrag[pos] = f2bf(w[i]);
}

// ---------------------------------------------------------------------------
// MFMA gemm: g[n][c] = sum_k f[n][k] w[c][k], output plain row-major bf16.
// One wave per 16-node tile, all 128 channels (8 ch-tiles x 4 k-steps).
// A-frag: lane holds f[m=lane&15][k=(lane>>4)*8 + j] (8 consecutive k, cvt'd).
// B-frag: fragment-ordered wfrag, coalesced dwordx4, L1/L2-hot (32 KB).
// D: col(c)=lane&15, row(node)=(lane>>4)*4+reg  [verified m89/m91].
__global__ __launch_bounds__(256) void gemm_kernel(
    const float* __restrict__ f, const unsigned short* __restrict__ wfrag,
    unsigned short* __restrict__ gb) {
  const int wv = blockIdx.x * 4 + (threadIdx.x >> 6);
  if (wv >= NTILE) return;
  const int lane = threadIdx.x & 63;
  const int mrow = lane & 15;
  const int q = lane >> 4;
  const long node = (long)wv * 16 + mrow;
  const float* fr = f + node * D + q * 8;

  bf16x8 a[4];
#pragma unroll
  for (int ks = 0; ks < 4; ++ks) {
    const float4 lo = *(const float4*)(fr + ks * 32);
    const float4 hi = *(const float4*)(fr + ks * 32 + 4);
    union { bf16x8 v; unsigned short u[8]; } pa;
    pa.u[0] = f2bf(lo.x); pa.u[1] = f2bf(lo.y);
    pa.u[2] = f2bf(lo.z); pa.u[3] = f2bf(lo.w);
    pa.u[4] = f2bf(hi.x); pa.u[5] = f2bf(hi.y);
    pa.u[6] = f2bf(hi.z); pa.u[7] = f2bf(hi.w);
    a[ks] = pa.v;
  }

  const long nbase = (long)wv * 16 + (q << 2);
#pragma unroll
  for (int tc = 0; tc < 8; ++tc) {
    f32x4 acc = {0.f, 0.f, 0.f, 0.f};
#pragma unroll
    for (int ks = 0; ks < 4; ++ks) {
      const bf16x8 b =
          *(const bf16x8*)(wfrag + (((tc << 2) + ks) * 64 + lane) * 8);
      acc = __builtin_amdgcn_mfma_f32_16x16x32_bf16(a[ks], b, acc, 0, 0, 0);
    }
    const int c = (tc << 4) + mrow;
#pragma unroll
    for (int r = 0; r < 4; ++r) gb[(nbase + r) * D + c] = f2bf(acc[r]);
  }
}

// ---------------------------------------------------------------------------
// Bucket histogram (1563 counters), LDS-aggregated int atomics.  (proven R5)
__global__ __launch_bounds__(256) void hist_kernel(const int* __restrict__ dst,
                                                   int* __restrict__ gcnt) {
  __shared__ int h[NBKT2];
  const int t = threadIdx.x;
  for (int b = t; b < NBKT2; b += 256) h[b] = 0;
  __syncthreads();
  const int base = blockIdx.x * 4096;
#pragma unroll
  for (int i = 0; i < 16; ++i) {
    int e = base + i * 256 + t;
    if (e < NE) atomicAdd(&h[dst[e] >> 6], 1);
  }
  __syncthreads();
  for (int b = t; b < NBKT2; b += 256)
    if (h[b]) atomicAdd(&gcnt[b], h[b]);
}

// Exclusive scan of 1563 counts.  (proven R5)
__global__ __launch_bounds__(1024) void scan_kernel(const int* __restrict__ gcnt,
                                                    int* __restrict__ bstart,
                                                    int* __restrict__ cur,
                                                    int* __restrict__ row_ptr) {
  __shared__ int s[2048];
  const int t = threadIdx.x;
  s[t] = (t < NBKT2) ? gcnt[t] : 0;
  s[t + 1024] = (t + 1024 < NBKT2) ? gcnt[t + 1024] : 0;
  __syncthreads();
  if (t < 64) {
    int part = 0;
#pragma unroll
    for (int i = 0; i < 32; ++i) part += s[(t << 5) + i];
    int inc = part;
#pragma unroll
    for (int off = 1; off < 64; off <<= 1) {
      int x = __shfl_up(inc, off, 64);
      if (t >= off) inc += x;
    }
    int run = inc - part;
#pragma unroll
    for (int i = 0; i < 32; ++i) {
      int idx = (t << 5) + i;
      int v = s[idx];
      s[idx] = run;
      run += v;
    }
  }
  __syncthreads();
  if (t < NBKT2) { bstart[t] = s[t]; cur[t] = s[t]; }
  if (t + 1024 < NBKT2) { bstart[t + 1024] = s[t + 1024]; cur[t + 1024] = s[t + 1024]; }
  if (t == 0) { bstart[NBKT2] = NE; row_ptr[NN] = NE; }
}

// ---------------------------------------------------------------------------
// Bin edges into buckets (dense runs).  (proven R5)
__global__ __launch_bounds__(512) void bin_kernel(
    const int* __restrict__ src, const int* __restrict__ dst,
    const float* __restrict__ norm, int* __restrict__ cur,
    int2* __restrict__ bufA) {
  __shared__ int bcnt[NBKT2];
  __shared__ int bbase[NBKT2];
  const int t = threadIdx.x;
  for (int b = t; b < NBKT2; b += 512) bcnt[b] = 0;
  __syncthreads();
  const int base = blockIdx.x * 16384;
#pragma unroll
  for (int i = 0; i < 32; ++i) {
    int e = base + i * 512 + t;
    if (e < NE) atomicAdd(&bcnt[dst[e] >> 6], 1);
  }
  __syncthreads();
  for (int b = t; b < NBKT2; b += 512) {
    int c = bcnt[b];
    if (c) bbase[b] = atomicAdd(&cur[b], c);
    bcnt[b] = 0;  // reuse as rank
  }
  __syncthreads();
#pragma unroll
  for (int i = 0; i < 32; ++i) {
    int e = base + i * 512 + t;
    if (e < NE) {
      int d = dst[e];
      int b = d >> 6;
      int r = atomicAdd(&bcnt[b], 1);
      int2 m;
      m.x = src[e] | ((d & 63) << 24);
      m.y = __float_as_int(norm[e]);
      bufA[bbase[b] + r] = m;
    }
  }
}

// ---------------------------------------------------------------------------
// Per-bucket counting sort by local node.  (proven R5)
__global__ __launch_bounds__(256) void sort_kernel(
    const int2* __restrict__ bufA, const int* __restrict__ bstart,
    int2* __restrict__ bufB, int* __restrict__ row_ptr) {
  __shared__ int lcnt[64];
  __shared__ int lbase[64];
  const int b = blockIdx.x;
  const int t = threadIdx.x;
  const int beg = bstart[b];
  const int end = bstart[b + 1];
  if (t < 64) lcnt[t] = 0;
  __syncthreads();
  for (int e = beg + t; e < end; e += 256) {
    int2 m = bufA[e];
    atomicAdd(&lcnt[(m.x >> 24) & 63], 1);
  }
  __syncthreads();
  if (t < 64) {
    int v = lcnt[t];
    int inc = v;
#pragma unroll
    for (int off = 1; off < 64; off <<= 1) {
      int x = __shfl_up(inc, off, 64);
      if (t >= off) inc += x;
    }
    int ex = inc - v;
    lbase[t] = ex;
    int n = (b << 6) + t;
    if (n < NN) row_ptr[n] = beg + ex;
    lcnt[t] = 0;
  }
  __syncthreads();
  for (int e = beg + t; e < end; e += 256) {
    int2 m = bufA[e];
    int nl = (m.x >> 24) & 63;
    int r = atomicAdd(&lcnt[nl], 1);
    int2 o;
    o.x = m.x & 0xFFFFFF;
    o.y = m.y;
    bufB[beg + lbase[nl] + r] = o;
  }
}

// ---------------------------------------------------------------------------
// Pull: one wave per node, lane owns channels {2*lane, 2*lane+1}. 8 edges in
// flight, register accumulators. No atomics, no LDS.  (R5 structure; layout
// updated for plain row-major gb)
__global__ __launch_bounds__(256) void pull_kernel(
    const unsigned short* __restrict__ gb, const int* __restrict__ row_ptr,
    const int2* __restrict__ bufB, const float* __restrict__ bias,
    float* __restrict__ out) {
  const int n = blockIdx.x * 4 + (threadIdx.x >> 6);
  if (n >= NN) return;
  const int lane = threadIdx.x & 63;
  const int beg = row_ptr[n];
  const int end = row_ptr[n + 1];

  float a0[8] = {0.f, 0.f, 0.f, 0.f, 0.f, 0.f, 0.f, 0.f};
  float a1[8] = {0.f, 0.f, 0.f, 0.f, 0.f, 0.f, 0.f, 0.f};

  for (int e0 = beg; e0 < end; e0 += 8) {
    int2 m[8];
    unsigned q[8];
#pragma unroll
    for (int j = 0; j < 8; ++j) m[j] = bufB[min(e0 + j, end - 1)];
#pragma unroll
    for (int j = 0; j < 8; ++j)
      q[j] = *(const unsigned*)(gb + ((long)m[j].x << 7) + (lane << 1));
#pragma unroll
    for (int j = 0; j < 8; ++j) {
      if (e0 + j < end) {  // wave-uniform guard
        const float nr = __int_as_float(m[j].y);
        a0[j] += nr * __uint_as_float(q[j] << 16);           // ch 2*lane
        a1[j] += nr * __uint_as_float(q[j] & 0xFFFF0000u);   // ch 2*lane+1
      }
    }
  }
  const float s0 = ((a0[0] + a0[1]) + (a0[2] + a0[3])) +
                   ((a0[4] + a0[5]) + (a0[6] + a0[7]));
  const float s1 = ((a1[0] + a1[1]) + (a1[2] + a1[3])) +
                   ((a1[4] + a1[5]) + (a1[6] + a1[7]));
  const float2 b2 = *(const float2*)(bias + (lane << 1));
  float2 r;
  r.x = s0 + b2.x;
  r.y = s1 + b2.y;
  *(float2*)(out + (long)n * D + (lane << 1)) = r;
}

// ---------------------------------------------------------------------------
// Fallback (ws too small): R1 path.
__global__ __launch_bounds__(256) void gemm_f32_kernel(
    const float* __restrict__ f, const float* __restrict__ w,
    float* __restrict__ g) {
  __shared__ float wlds[D * D];
  const int t = threadIdx.x;
  for (int i = t; i < D * D; i += 256) {
    int c = i >> 7, k = i & 127;
    wlds[(c << 7) + (k ^ (c & 31))] = w[i];
  }
  __syncthreads();
  const int c = t & 127;
  const int cx = c & 31;
  const int cbase = c << 7;
  const int jbase = __builtin_amdgcn_readfirstlane((t >> 7) << 3);
  const long nb = (long)blockIdx.x * 16 + jbase;
  const float* __restrict__ frow = f + nb * D;
  float acc[8] = {0.f, 0.f, 0.f, 0.f, 0.f, 0.f, 0.f, 0.f};
#pragma unroll 4
  for (int k = 0; k < D; ++k) {
    float wv = wlds[cbase + (k ^ cx)];
#pragma unroll
    for (int j = 0; j < 8; ++j) acc[j] += frow[j * D + k] * wv;
  }
#pragma unroll
  for (int j = 0; j < 8; ++j) g[(nb + j) * D + c] = acc[j];
}

__global__ __launch_bounds__(256) void init_kernel(
    const float* __restrict__ bias, float4* __restrict__ out) {
  const int i = blockIdx.x * 256 + threadIdx.x;
  const float4* b4 = (const float4*)bias;
  out[i] = b4[i & 31];
}

__global__ __launch_bounds__(256) void scatter_kernel(
    const float* __restrict__ g, const float* __restrict__ norm,
    const int* __restrict__ src, const int* __restrict__ dst,
    float* __restrict__ out) {
  const long tid = (long)blockIdx.x * 256 + threadIdx.x;
  const int e = (int)(tid >> 5);
  if (e >= NE) return;
  const int ch = (int)(tid & 31) << 2;
  const int s = src[e];
  const int d = dst[e];
  const float nr = norm[e];
  const float4 gv = *(const float4*)(g + (long)s * D + ch);
  float* op = out + (long)d * D + ch;
  unsafeAtomicAdd(op + 0, nr * gv.x);
  unsafeAtomicAdd(op + 1, nr * gv.y);
  unsafeAtomicAdd(op + 2, nr * gv.z);
  unsafeAtomicAdd(op + 3, nr * gv.w);
}

// ---------------------------------------------------------------------------
extern "C" void kernel_launch(void* const* d_in, const int* in_sizes, int n_in,
                              void* d_out, int out_size, void* d_ws,
                              size_t ws_size, hipStream_t stream) {
  const float* features = (const float*)d_in[0];
  const float* norm     = (const float*)d_in[1];
  const int*   src      = (const int*)d_in[2];
  const int*   dst      = (const int*)d_in[3];
  const float* weight   = (const float*)d_in[4];
  const float* bias     = (const float*)d_in[5];
  float* out = (float*)d_out;

  char* ws = (char*)d_ws;
  unsigned short* gb    = (unsigned short*)ws;   // [0, 25.6M)
  int2* bufA    = (int2*)(ws + 25600000);        // [25.6M, 51.2M)
  int2* bufB    = (int2*)(ws + 51200000);        // [51.2M, 76.8M)
  int*  row_ptr = (int*)(ws + 76800000);         // 400,004 B
  int*  gcnt    = (int*)(ws + 77200008);         // 6,252 B
  int*  bstart  = (int*)(ws + 77206264);         // 6,256 B
  int*  cur     = (int*)(ws + 77212524);         // 6,252 B
  unsigned short* wfrag = (unsigned short*)(ws + 77218784);  // 32,768 B
  const size_t need = 77251552;                  // ws >= 77,602,176 proven (R2)

  if (ws_size >= need) {
    hipMemsetAsync(gcnt, 0, NBKT2 * sizeof(int), stream);
    hipLaunchKernelGGL(cvtw_kernel, dim3(64), dim3(256), 0, stream,
                       weight, wfrag);
    hipLaunchKernelGGL(gemm_kernel, dim3((NTILE + 3) / 4), dim3(256), 0,
                       stream, features, wfrag, gb);
    hipLaunchKernelGGL(hist_kernel, dim3((NE + 4095) / 4096), dim3(256), 0,
                       stream, dst, gcnt);
    hipLaunchKernelGGL(scan_kernel, dim3(1), dim3(1024), 0, stream,
                       gcnt, bstart, cur, row_ptr);
    hipLaunchKernelGGL(bin_kernel, dim3((NE + 16383) / 16384), dim3(512), 0,
                       stream, src, dst, norm, cur, bufA);
    hipLaunchKernelGGL(sort_kernel, dim3(NBKT2), dim3(256), 0, stream,
                       bufA, bstart, bufB, row_ptr);
    hipLaunchKernelGGL(pull_kernel, dim3((NN + 3) / 4), dim3(256), 0, stream,
                       gb, row_ptr, bufB, bias, out);
  } else {
    float* g = (float*)ws;
    hipLaunchKernelGGL(gemm_f32_kernel, dim3(NN / 16), dim3(256), 0, stream,
                       features, weight, g);
    hipLaunchKernelGGL(init_kernel, dim3((NN * D / 4) / 256), dim3(256), 0,
                       stream, bias, (float4*)out);
    hipLaunchKernelGGL(scatter_kernel, dim3((long)NE * 32 / 256), dim3(256), 0,
                       stream, g, norm, src, dst, out);
  }
}